// Round 10
// baseline (528.344 us; speedup 1.0000x reference)
//
#include <hip/hip_runtime.h>
#include <cstdint>
#include <cstddef>

typedef _Float16 f16;
typedef __attribute__((ext_vector_type(8))) _Float16 f16x8;
typedef __attribute__((ext_vector_type(4))) _Float16 f16x4;
typedef __attribute__((ext_vector_type(4))) float f32x4;

#define MFMA_F16(a, b, c) __builtin_amdgcn_mfma_f32_16x16x32_f16((a), (b), (c), 0, 0, 0)

#define GL2LDS(gsrc, ldst)                                                  \
    __builtin_amdgcn_global_load_lds(                                        \
        (const __attribute__((address_space(1))) void*)(gsrc),               \
        (__attribute__((address_space(3))) void*)(ldst), 16, 0, 0)

#define WAITV(n) asm volatile("s_waitcnt vmcnt(" #n ")" ::: "memory")
#define BAR() __builtin_amdgcn_s_barrier()
#define PRIO(n) __builtin_amdgcn_s_setprio(n)

// bank swizzle for 64B rows (verified R5: conflicts 2.1e7 -> 0)
#define SWZ(row) (((row) >> 1) & 3)

// ws layout (f16 elems): [0,262144) W_L | [262144,524288) W_R |
//   [524288,786432) W_out | xt at elem 1<<20: 8 blade planes of [16384][512].
// gp (f16) in d_out: batch b at byte b*16384, blade i at +i*1024, ch n at +2n.
//
// SAFETY RULE (R9 lesson): LDS staging is ALWAYS issued at the TOP of the
// iteration with 3 buffers — the written buffer was last read one full
// barrier-pair earlier, so correctness never depends on s_barrier acting as
// a compiler fence. No register copies of in-flight loads (static bregs).

// ---------------------------------------------------------------------------
// k0: blocks 0..8191 transpose x [b][m][i] f32 -> xt [i][b][m] f16;
//     blocks 8192..9215 convert the three weight matrices.
// ---------------------------------------------------------------------------
__global__ __launch_bounds__(256) void k0(const float* __restrict__ x,
                                          const float* __restrict__ wl,
                                          const float* __restrict__ wr,
                                          const float* __restrict__ wo,
                                          f16* __restrict__ wdst,
                                          f16* __restrict__ xt) {
    const int bid = blockIdx.x;
    if (bid >= 8192) {
        int i = (bid - 8192) * 256 + threadIdx.x;
        wdst[i]          = (f16)wl[i];
        wdst[262144 + i] = (f16)wr[i];
        wdst[524288 + i] = (f16)wo[i];
        return;
    }
    const int b = (bid >> 1) * 4 + (threadIdx.x >> 6);
    const int m = (bid & 1) * 256 + (threadIdx.x & 63) * 4;
    const float* src = x + ((size_t)b * 512 + m) * 8;
    f32x4 v[8];
#pragma unroll
    for (int u = 0; u < 8; ++u) v[u] = *(const f32x4*)(src + u * 4);
#pragma unroll
    for (int i = 0; i < 8; ++i) {
        f16x4 w;
#pragma unroll
        for (int j = 0; j < 4; ++j) w[j] = (f16)v[j * 2 + (i >> 2)][i & 3];
        *(f16x4*)(xt + (size_t)i * 8388608 + (size_t)b * 512 + m) = w;
    }
}

// ---------------------------------------------------------------------------
// k1: vec_L/vec_R GEMMs + geometric product. Block 32 b x 128 ch, 1024 thr /
// 16 waves (wb2 x wn8); wave = 16b x 16ch BOTH sides, acc[8][2] = 64 regs.
// A staged global_load_lds (1 call/tile, 3 bufs, top-issued, 2 ahead);
// B (L2-resident W) direct global->reg, static bregs[kt&1], 1 ahead.
// Waits (per-wave FIFO: 1 stage + 2 B per iter): steady 3, kt=14: 2, kt=15: 0.
// ---------------------------------------------------------------------------
__global__ __launch_bounds__(1024, 4) void k1(
    const f16* __restrict__ xt, const f16* __restrict__ wf,
    const float* __restrict__ bl_p, const float* __restrict__ br_p,
    char* gp_out)
{
    __shared__ __align__(16) f16 AsF[3 * 8192];   // [buf][blade8][bat32][k32] 48KB

    const int L = blockIdx.x;                     // 0..2047, XCD-chunked
    const int xcd = L & 7, sl = L >> 3;
    const int bt = xcd * 64 + (sl >> 2), ct = sl & 3;
    const int b0 = bt * 32, n0 = ct * 128;

    const int tid = threadIdx.x, lane = tid & 63, wv = tid >> 6;  // wv 0..15
    const int wb = wv >> 3, wn = wv & 7;
    const int r_lo = lane & 15, s_hi = lane >> 4;

    // A staging source (1 call x 1024 lanes = 16KB tile), swizzle keyed on bat
    const int ab = tid >> 7, arw = (tid >> 2) & 31, ac = (tid & 3) ^ SWZ(arw);
    const f16* aS = xt + (size_t)ab * 8388608 + (size_t)(b0 + arw) * 512 + ac * 8;
    f16* aD = AsF + wv * 512;                     // wave-uniform; HW adds lane*16B

    // A compute-side LDS offset
    const int ar = wb * 16 + r_lo;
    const int arow = ar * 32 + ((s_hi ^ SWZ(ar)) << 3);   // + blade*1024 + buf*8192

    // B direct pointers (this wave's 16-ch strip, both sides)
    const int chrow = n0 + wn * 16 + r_lo;
    const f16* bPL = wf + (size_t)chrow * 512 + s_hi * 8;
    const f16* bPR = bPL + 262144;

    f32x4 acc[8][2];
    const f32x4 zero = {0.f, 0.f, 0.f, 0.f};
#pragma unroll
    for (int i = 0; i < 8; ++i) { acc[i][0] = zero; acc[i][1] = zero; }

    auto stageA = [&](int kt, int buf) { GL2LDS(aS + kt * 32, aD + buf * 8192); };

    f16x8 bregs[2][2];    // [tile parity][side] — statically indexed under unroll
    stageA(0, 0);
    bregs[0][0] = *(const f16x8*)bPL;
    bregs[0][1] = *(const f16x8*)bPR;
    stageA(1, 1);

#pragma unroll
    for (int kt = 0; kt < 16; ++kt) {
        // ---- top: issue next-tile loads (never after a barrier) ----
        if (kt + 2 < 16) stageA(kt + 2, (kt + 2) % 3);
        if (kt < 15) {
            bregs[(kt + 1) & 1][0] = *(const f16x8*)(bPL + (kt + 1) * 32);
            bregs[(kt + 1) & 1][1] = *(const f16x8*)(bPR + (kt + 1) * 32);
        }
        if (kt <= 13)      { WAITV(3); }
        else if (kt == 14) { WAITV(2); }
        else               { WAITV(0); }
        BAR();
        const f16* Ab = AsF + (kt % 3) * 8192;
        const f16x8 bL = bregs[kt & 1][0];
        const f16x8 bR = bregs[kt & 1][1];
        {   // blades 0-3
            f16x8 a0 = *(const f16x8*)(Ab + 0 * 1024 + arow);
            f16x8 a1 = *(const f16x8*)(Ab + 1 * 1024 + arow);
            f16x8 a2 = *(const f16x8*)(Ab + 2 * 1024 + arow);
            f16x8 a3 = *(const f16x8*)(Ab + 3 * 1024 + arow);
            PRIO(1);
            acc[0][0] = MFMA_F16(a0, bL, acc[0][0]); acc[0][1] = MFMA_F16(a0, bR, acc[0][1]);
            acc[1][0] = MFMA_F16(a1, bL, acc[1][0]); acc[1][1] = MFMA_F16(a1, bR, acc[1][1]);
            acc[2][0] = MFMA_F16(a2, bL, acc[2][0]); acc[2][1] = MFMA_F16(a2, bR, acc[2][1]);
            acc[3][0] = MFMA_F16(a3, bL, acc[3][0]); acc[3][1] = MFMA_F16(a3, bR, acc[3][1]);
            PRIO(0);
        }
        {   // blades 4-7
            f16x8 a4 = *(const f16x8*)(Ab + 4 * 1024 + arow);
            f16x8 a5 = *(const f16x8*)(Ab + 5 * 1024 + arow);
            f16x8 a6 = *(const f16x8*)(Ab + 6 * 1024 + arow);
            f16x8 a7 = *(const f16x8*)(Ab + 7 * 1024 + arow);
            PRIO(1);
            acc[4][0] = MFMA_F16(a4, bL, acc[4][0]); acc[4][1] = MFMA_F16(a4, bR, acc[4][1]);
            acc[5][0] = MFMA_F16(a5, bL, acc[5][0]); acc[5][1] = MFMA_F16(a5, bR, acc[5][1]);
            acc[6][0] = MFMA_F16(a6, bL, acc[6][0]); acc[6][1] = MFMA_F16(a6, bR, acc[6][1]);
            acc[7][0] = MFMA_F16(a7, bL, acc[7][0]); acc[7][1] = MFMA_F16(a7, bR, acc[7][1]);
            PRIO(0);
        }
        BAR();
    }

    // epilogue: bias + Cl(3,0) geometric product -> gp f16 in d_out
    const float blv = bl_p[chrow], brv = br_p[chrow];
#pragma unroll
    for (int rr = 0; rr < 4; ++rr) {
        const int b_g = b0 + wb * 16 + s_hi * 4 + rr;
        float Lv[8], Rv[8];
#pragma unroll
        for (int i = 0; i < 8; ++i) { Lv[i] = acc[i][0][rr]; Rv[i] = acc[i][1][rr]; }
        Lv[0] += blv; Rv[0] += brv;
        float g[8];
        g[0] = Lv[0]*Rv[0]+Lv[1]*Rv[1]+Lv[2]*Rv[2]+Lv[3]*Rv[3]-Lv[4]*Rv[4]-Lv[5]*Rv[5]-Lv[6]*Rv[6]-Lv[7]*Rv[7];
        g[1] = Lv[0]*Rv[1]+Lv[1]*Rv[0]-Lv[2]*Rv[4]-Lv[3]*Rv[5]+Lv[4]*Rv[2]+Lv[5]*Rv[3]-Lv[6]*Rv[7]-Lv[7]*Rv[6];
        g[2] = Lv[0]*Rv[2]+Lv[1]*Rv[4]+Lv[2]*Rv[0]-Lv[3]*Rv[6]-Lv[4]*Rv[1]+Lv[5]*Rv[7]+Lv[6]*Rv[3]+Lv[7]*Rv[5];
        g[3] = Lv[0]*Rv[3]+Lv[1]*Rv[5]+Lv[2]*Rv[6]+Lv[3]*Rv[0]-Lv[4]*Rv[7]-Lv[5]*Rv[1]-Lv[6]*Rv[2]-Lv[7]*Rv[4];
        g[4] = Lv[0]*Rv[4]+Lv[1]*Rv[2]-Lv[2]*Rv[1]+Lv[3]*Rv[7]+Lv[4]*Rv[0]-Lv[5]*Rv[6]+Lv[6]*Rv[5]+Lv[7]*Rv[3];
        g[5] = Lv[0]*Rv[5]+Lv[1]*Rv[3]-Lv[2]*Rv[7]-Lv[3]*Rv[1]+Lv[4]*Rv[6]+Lv[5]*Rv[0]-Lv[6]*Rv[4]-Lv[7]*Rv[2];
        g[6] = Lv[0]*Rv[6]+Lv[1]*Rv[7]+Lv[2]*Rv[3]-Lv[3]*Rv[2]-Lv[4]*Rv[5]+Lv[5]*Rv[4]+Lv[6]*Rv[0]+Lv[7]*Rv[1];
        g[7] = Lv[0]*Rv[7]+Lv[1]*Rv[6]-Lv[2]*Rv[5]+Lv[3]*Rv[4]+Lv[4]*Rv[3]-Lv[5]*Rv[2]+Lv[6]*Rv[1]+Lv[7]*Rv[0];
        char* dst = gp_out + (size_t)b_g * 16384 + (size_t)chrow * 2;
#pragma unroll
        for (int i = 0; i < 8; ++i) *(f16*)(dst + (size_t)i * 1024) = (f16)g[i];
    }
}

// ---------------------------------------------------------------------------
// k2: out = gp @ W_out^T + bias, MVLayerNorm, scale.
// Block 16 b x 512 ch, 1024 thr / 16 waves, wave = 16b x 32ch, acc[8][2].
// A (gp) staged via global_load_lds (waves 0-7, 3 bufs, top-issued);
// B (W_out rows, per-wave-exclusive) direct global->reg, static bregs.
// ---------------------------------------------------------------------------
__global__ __launch_bounds__(1024, 4) void k2(
    const char* gp_in, const f16* __restrict__ wo,
    const float* __restrict__ bo_p, const float* __restrict__ an_p,
    float* outp)
{
    __shared__ __align__(16) f16 AsF[3 * 4096];    // [buf][blade8][bat16][k32] 24KB
    __shared__ float red[16][16];

    const int b0 = blockIdx.x * 16;
    const int tid = threadIdx.x, lane = tid & 63, wv = tid >> 6;   // wv 0..15
    const int r_lo = lane & 15, s_hi = lane >> 4;

    // A staging (tid<512, 1 call = 8KB tile)
    const int abl = tid >> 6, arw = (tid >> 2) & 15, agp = (tid & 3) ^ SWZ(arw);
    const char* aS = gp_in + (size_t)(b0 + arw) * 16384 + (size_t)(abl & 7) * 1024 + agp * 16;
    f16* aD = AsF + wv * 512;    // used by wv<8 only

    // A compute-side LDS offset
    const int aoff = r_lo * 32 + ((s_hi ^ SWZ(r_lo)) << 3);   // + blade*512 + buf*4096

    // B direct pointers (per-wave-exclusive W_out rows)
    const int nl0 = wv * 32 + r_lo, nl1 = nl0 + 16;
    const f16* bQ0 = wo + (size_t)nl0 * 512 + s_hi * 8;
    const f16* bQ1 = wo + (size_t)nl1 * 512 + s_hi * 8;

    f32x4 acc[8][2];
    const f32x4 zero = {0.f, 0.f, 0.f, 0.f};
#pragma unroll
    for (int i = 0; i < 8; ++i) { acc[i][0] = zero; acc[i][1] = zero; }

    auto stageA = [&](int kt, int buf) {
        if (tid < 512) GL2LDS(aS + (size_t)kt * 64, aD + buf * 4096);
    };

    f16x8 bregs[2][2];
    stageA(0, 0);
    bregs[0][0] = *(const f16x8*)bQ0;
    bregs[0][1] = *(const f16x8*)bQ1;
    stageA(1, 1);

#pragma unroll
    for (int kt = 0; kt < 16; ++kt) {
        if (kt + 2 < 16) stageA(kt + 2, (kt + 2) % 3);
        if (kt < 15) {
            bregs[(kt + 1) & 1][0] = *(const f16x8*)(bQ0 + (kt + 1) * 32);
            bregs[(kt + 1) & 1][1] = *(const f16x8*)(bQ1 + (kt + 1) * 32);
        }
        if (kt <= 13)      { if (wv < 8) { WAITV(3); } else { WAITV(2); } }
        else if (kt == 14) { WAITV(2); }
        else               { WAITV(0); }
        BAR();
        const f16* Ab = AsF + (kt % 3) * 4096;
        const f16x8 b0f = bregs[kt & 1][0];
        const f16x8 b1f = bregs[kt & 1][1];
        {   // blades 0-3
            f16x8 a0 = *(const f16x8*)(Ab + 0 * 512 + aoff);
            f16x8 a1 = *(const f16x8*)(Ab + 1 * 512 + aoff);
            f16x8 a2 = *(const f16x8*)(Ab + 2 * 512 + aoff);
            f16x8 a3 = *(const f16x8*)(Ab + 3 * 512 + aoff);
            PRIO(1);
            acc[0][0] = MFMA_F16(a0, b0f, acc[0][0]); acc[0][1] = MFMA_F16(a0, b1f, acc[0][1]);
            acc[1][0] = MFMA_F16(a1, b0f, acc[1][0]); acc[1][1] = MFMA_F16(a1, b1f, acc[1][1]);
            acc[2][0] = MFMA_F16(a2, b0f, acc[2][0]); acc[2][1] = MFMA_F16(a2, b1f, acc[2][1]);
            acc[3][0] = MFMA_F16(a3, b0f, acc[3][0]); acc[3][1] = MFMA_F16(a3, b1f, acc[3][1]);
            PRIO(0);
        }
        {   // blades 4-7
            f16x8 a4 = *(const f16x8*)(Ab + 4 * 512 + aoff);
            f16x8 a5 = *(const f16x8*)(Ab + 5 * 512 + aoff);
            f16x8 a6 = *(const f16x8*)(Ab + 6 * 512 + aoff);
            f16x8 a7 = *(const f16x8*)(Ab + 7 * 512 + aoff);
            PRIO(1);
            acc[4][0] = MFMA_F16(a4, b0f, acc[4][0]); acc[4][1] = MFMA_F16(a4, b1f, acc[4][1]);
            acc[5][0] = MFMA_F16(a5, b0f, acc[5][0]); acc[5][1] = MFMA_F16(a5, b1f, acc[5][1]);
            acc[6][0] = MFMA_F16(a6, b0f, acc[6][0]); acc[6][1] = MFMA_F16(a6, b1f, acc[6][1]);
            acc[7][0] = MFMA_F16(a7, b0f, acc[7][0]); acc[7][1] = MFMA_F16(a7, b1f, acc[7][1]);
            PRIO(0);
        }
        BAR();
    }

    const float bo0 = bo_p[nl0], bo1 = bo_p[nl1];
    const float an0 = an_p[nl0], an1 = an_p[nl1];

    float partial[4];
#pragma unroll
    for (int rr = 0; rr < 4; ++rr) {
        float o = acc[0][0][rr] + bo0;
        float ss = o * o;
#pragma unroll
        for (int i = 1; i < 8; ++i) ss += acc[i][0][rr] * acc[i][0][rr];
        float s = sqrtf(ss);
        o = acc[0][1][rr] + bo1;
        ss = o * o;
#pragma unroll
        for (int i = 1; i < 8; ++i) ss += acc[i][1][rr] * acc[i][1][rr];
        partial[rr] = s + sqrtf(ss);
    }
#pragma unroll
    for (int off = 1; off < 16; off <<= 1)
#pragma unroll
        for (int rr = 0; rr < 4; ++rr) partial[rr] += __shfl_xor(partial[rr], off);
    if (r_lo == 0)
#pragma unroll
        for (int rr = 0; rr < 4; ++rr) red[s_hi * 4 + rr][wv] = partial[rr];
    __syncthreads();   // full fence: all gp reads done before fp32 stores

#pragma unroll
    for (int rr = 0; rr < 4; ++rr) {
        float tot = 0.f;
#pragma unroll
        for (int w = 0; w < 16; ++w) tot += red[s_hi * 4 + rr][w];
        const float inv = 1.0f / (tot * (1.0f / 512.0f) + 1e-6f);
        const float sc0 = an0 * inv, sc1 = an1 * inv;
        const int b_g = b0 + s_hi * 4 + rr;
        float* dst = outp + (size_t)b_g * 4096;
        f32x4 v;
        v[0] = (acc[0][0][rr] + bo0) * sc0;
        v[1] = acc[1][0][rr] * sc0; v[2] = acc[2][0][rr] * sc0; v[3] = acc[3][0][rr] * sc0;
        *(f32x4*)(dst + (size_t)nl0 * 8) = v;
        v[0] = acc[4][0][rr] * sc0; v[1] = acc[5][0][rr] * sc0;
        v[2] = acc[6][0][rr] * sc0; v[3] = acc[7][0][rr] * sc0;
        *(f32x4*)(dst + (size_t)nl0 * 8 + 4) = v;
        v[0] = (acc[0][1][rr] + bo1) * sc1;
        v[1] = acc[1][1][rr] * sc1; v[2] = acc[2][1][rr] * sc1; v[3] = acc[3][1][rr] * sc1;
        *(f32x4*)(dst + (size_t)nl1 * 8) = v;
        v[0] = acc[4][1][rr] * sc1; v[1] = acc[5][1][rr] * sc1;
        v[2] = acc[6][1][rr] * sc1; v[3] = acc[7][1][rr] * sc1;
        *(f32x4*)(dst + (size_t)nl1 * 8 + 4) = v;
    }
}

// ---------------------------------------------------------------------------
extern "C" void kernel_launch(void* const* d_in, const int* in_sizes, int n_in,
                              void* d_out, int out_size, void* d_ws, size_t ws_size,
                              hipStream_t stream) {
    const float* x  = (const float*)d_in[0];
    const float* wl = (const float*)d_in[1];
    const float* bl = (const float*)d_in[2];
    const float* wr = (const float*)d_in[3];
    const float* br = (const float*)d_in[4];
    const float* wo = (const float*)d_in[5];
    const float* bo = (const float*)d_in[6];
    const float* an = (const float*)d_in[7];
    f16* wf = (f16*)d_ws;
    f16* xt = wf + (1 << 20);   // byte offset 2MB; ws >= 130MB (confirmed R3)

    hipLaunchKernelGGL(k0, dim3(9216), dim3(256), 0, stream, x, wl, wr, wo, wf, xt);
    hipLaunchKernelGGL(k1, dim3(2048), dim3(1024), 0, stream, xt, wf, bl, br, (char*)d_out);
    hipLaunchKernelGGL(k2, dim3(1024), dim3(1024), 0, stream,
                       (const char*)d_out, wf + 524288, bo, an, (float*)d_out);
}

// Round 11
// 501.162 us; speedup vs baseline: 1.0542x; 1.0542x over previous
//
#include <hip/hip_runtime.h>
#include <cstdint>
#include <cstddef>

typedef _Float16 f16;
typedef __attribute__((ext_vector_type(8))) _Float16 f16x8;
typedef __attribute__((ext_vector_type(4))) _Float16 f16x4;
typedef __attribute__((ext_vector_type(4))) float f32x4;

#define MFMA_F16(a, b, c) __builtin_amdgcn_mfma_f32_16x16x32_f16((a), (b), (c), 0, 0, 0)

#define GL2LDS(gsrc, ldst)                                                  \
    __builtin_amdgcn_global_load_lds(                                        \
        (const __attribute__((address_space(1))) void*)(gsrc),               \
        (__attribute__((address_space(3))) void*)(ldst), 16, 0, 0)

#define WAITV(n) asm volatile("s_waitcnt vmcnt(" #n ")" ::: "memory")
#define BAR() __builtin_amdgcn_s_barrier()
#define PRIO(n) __builtin_amdgcn_s_setprio(n)

// bank swizzle for 64B rows (verified R5: conflicts 2.1e7 -> 0)
#define SWZ(row) (((row) >> 1) & 3)

// ws layout (f16 elems): [0,262144) W_L | [262144,524288) W_R |
//   [524288,786432) W_out | xt at elem 1<<20: 8 blade planes of [16384][512].
// gp (f16) in d_out: batch b at byte b*16384, blade i at +i*1024, ch n at +2n.
//
// SAFETY (R9 lesson): staging issued at TOP of iteration, 3 buffers.
// FIFO ORDER (R10 lesson): B-reg loads issued BEFORE the A stage each
// iteration, so the counted wait for B(kt) does NOT drag in stage(kt+1).
// Steady state per iter: issue [B(kt+1) x2, stage(kt+2)]; WAITV(4) completes
// exactly {stage(kt), B(kt)} — A has 2 iterations of HBM slack, B has 1 of L2.

// ---------------------------------------------------------------------------
// k0: blocks 0..8191 transpose x [b][m][i] f32 -> xt [i][b][m] f16;
//     blocks 8192..9215 convert the three weight matrices.
// ---------------------------------------------------------------------------
__global__ __launch_bounds__(256) void k0(const float* __restrict__ x,
                                          const float* __restrict__ wl,
                                          const float* __restrict__ wr,
                                          const float* __restrict__ wo,
                                          f16* __restrict__ wdst,
                                          f16* __restrict__ xt) {
    const int bid = blockIdx.x;
    if (bid >= 8192) {
        int i = (bid - 8192) * 256 + threadIdx.x;
        wdst[i]          = (f16)wl[i];
        wdst[262144 + i] = (f16)wr[i];
        wdst[524288 + i] = (f16)wo[i];
        return;
    }
    const int b = (bid >> 1) * 4 + (threadIdx.x >> 6);
    const int m = (bid & 1) * 256 + (threadIdx.x & 63) * 4;
    const float* src = x + ((size_t)b * 512 + m) * 8;
    f32x4 v[8];
#pragma unroll
    for (int u = 0; u < 8; ++u) v[u] = *(const f32x4*)(src + u * 4);
#pragma unroll
    for (int i = 0; i < 8; ++i) {
        f16x4 w;
#pragma unroll
        for (int j = 0; j < 4; ++j) w[j] = (f16)v[j * 2 + (i >> 2)][i & 3];
        *(f16x4*)(xt + (size_t)i * 8388608 + (size_t)b * 512 + m) = w;
    }
}

// ---------------------------------------------------------------------------
// k1: vec_L/vec_R GEMMs + geometric product. Block 32 b x 128 ch, 1024 thr /
// 16 waves (wb2 x wn8); wave = 16b x 16ch BOTH sides, acc[8][2] = 64 regs.
// A staged global_load_lds (1 call/tile, 3 bufs, 2 ahead);
// B (L2-resident W) direct global->reg, static bregs[kt&1], 1 ahead.
// Issue order per iter: B(kt+1) x2 FIRST, then stage(kt+2).
// Waits: steady WAITV(4), kt=14: 3, kt=15: 0.
// ---------------------------------------------------------------------------
__global__ __launch_bounds__(1024, 4) void k1(
    const f16* __restrict__ xt, const f16* __restrict__ wf,
    const float* __restrict__ bl_p, const float* __restrict__ br_p,
    char* gp_out)
{
    __shared__ __align__(16) f16 AsF[3 * 8192];   // [buf][blade8][bat32][k32] 48KB

    const int L = blockIdx.x;                     // 0..2047, XCD-chunked
    const int xcd = L & 7, sl = L >> 3;
    const int bt = xcd * 64 + (sl >> 2), ct = sl & 3;
    const int b0 = bt * 32, n0 = ct * 128;

    const int tid = threadIdx.x, lane = tid & 63, wv = tid >> 6;  // wv 0..15
    const int wb = wv >> 3, wn = wv & 7;
    const int r_lo = lane & 15, s_hi = lane >> 4;

    // A staging source (1 call x 1024 lanes = 16KB tile), swizzle keyed on bat
    const int ab = tid >> 7, arw = (tid >> 2) & 31, ac = (tid & 3) ^ SWZ(arw);
    const f16* aS = xt + (size_t)ab * 8388608 + (size_t)(b0 + arw) * 512 + ac * 8;
    f16* aD = AsF + wv * 512;                     // wave-uniform; HW adds lane*16B

    // A compute-side LDS offset
    const int ar = wb * 16 + r_lo;
    const int arow = ar * 32 + ((s_hi ^ SWZ(ar)) << 3);   // + blade*1024 + buf*8192

    // B direct pointers (this wave's 16-ch strip, both sides)
    const int chrow = n0 + wn * 16 + r_lo;
    const f16* bPL = wf + (size_t)chrow * 512 + s_hi * 8;
    const f16* bPR = bPL + 262144;

    f32x4 acc[8][2];
    const f32x4 zero = {0.f, 0.f, 0.f, 0.f};
#pragma unroll
    for (int i = 0; i < 8; ++i) { acc[i][0] = zero; acc[i][1] = zero; }

    auto stageA = [&](int kt, int buf) { GL2LDS(aS + kt * 32, aD + buf * 8192); };

    f16x8 bregs[2][2];    // [tile parity][side] — statically indexed under unroll
    // prologue, FIFO = steady pattern: B first, then stages
    bregs[0][0] = *(const f16x8*)bPL;
    bregs[0][1] = *(const f16x8*)bPR;
    stageA(0, 0);
    stageA(1, 1);

#pragma unroll
    for (int kt = 0; kt < 16; ++kt) {
        // ---- top: B loads FIRST (oldest in this iter's FIFO slice) ----
        if (kt < 15) {
            bregs[(kt + 1) & 1][0] = *(const f16x8*)(bPL + (kt + 1) * 32);
            bregs[(kt + 1) & 1][1] = *(const f16x8*)(bPR + (kt + 1) * 32);
        }
        if (kt + 2 < 16) stageA(kt + 2, (kt + 2) % 3);
        if (kt <= 13)      { WAITV(4); }
        else if (kt == 14) { WAITV(3); }
        else               { WAITV(0); }
        BAR();
        const f16* Ab = AsF + (kt % 3) * 8192;
        const f16x8 bL = bregs[kt & 1][0];
        const f16x8 bR = bregs[kt & 1][1];
        {   // blades 0-3
            f16x8 a0 = *(const f16x8*)(Ab + 0 * 1024 + arow);
            f16x8 a1 = *(const f16x8*)(Ab + 1 * 1024 + arow);
            f16x8 a2 = *(const f16x8*)(Ab + 2 * 1024 + arow);
            f16x8 a3 = *(const f16x8*)(Ab + 3 * 1024 + arow);
            PRIO(1);
            acc[0][0] = MFMA_F16(a0, bL, acc[0][0]); acc[0][1] = MFMA_F16(a0, bR, acc[0][1]);
            acc[1][0] = MFMA_F16(a1, bL, acc[1][0]); acc[1][1] = MFMA_F16(a1, bR, acc[1][1]);
            acc[2][0] = MFMA_F16(a2, bL, acc[2][0]); acc[2][1] = MFMA_F16(a2, bR, acc[2][1]);
            acc[3][0] = MFMA_F16(a3, bL, acc[3][0]); acc[3][1] = MFMA_F16(a3, bR, acc[3][1]);
            PRIO(0);
        }
        {   // blades 4-7
            f16x8 a4 = *(const f16x8*)(Ab + 4 * 1024 + arow);
            f16x8 a5 = *(const f16x8*)(Ab + 5 * 1024 + arow);
            f16x8 a6 = *(const f16x8*)(Ab + 6 * 1024 + arow);
            f16x8 a7 = *(const f16x8*)(Ab + 7 * 1024 + arow);
            PRIO(1);
            acc[4][0] = MFMA_F16(a4, bL, acc[4][0]); acc[4][1] = MFMA_F16(a4, bR, acc[4][1]);
            acc[5][0] = MFMA_F16(a5, bL, acc[5][0]); acc[5][1] = MFMA_F16(a5, bR, acc[5][1]);
            acc[6][0] = MFMA_F16(a6, bL, acc[6][0]); acc[6][1] = MFMA_F16(a6, bR, acc[6][1]);
            acc[7][0] = MFMA_F16(a7, bL, acc[7][0]); acc[7][1] = MFMA_F16(a7, bR, acc[7][1]);
            PRIO(0);
        }
        BAR();
    }

    // epilogue: bias + Cl(3,0) geometric product -> gp f16 in d_out
    const float blv = bl_p[chrow], brv = br_p[chrow];
#pragma unroll
    for (int rr = 0; rr < 4; ++rr) {
        const int b_g = b0 + wb * 16 + s_hi * 4 + rr;
        float Lv[8], Rv[8];
#pragma unroll
        for (int i = 0; i < 8; ++i) { Lv[i] = acc[i][0][rr]; Rv[i] = acc[i][1][rr]; }
        Lv[0] += blv; Rv[0] += brv;
        float g[8];
        g[0] = Lv[0]*Rv[0]+Lv[1]*Rv[1]+Lv[2]*Rv[2]+Lv[3]*Rv[3]-Lv[4]*Rv[4]-Lv[5]*Rv[5]-Lv[6]*Rv[6]-Lv[7]*Rv[7];
        g[1] = Lv[0]*Rv[1]+Lv[1]*Rv[0]-Lv[2]*Rv[4]-Lv[3]*Rv[5]+Lv[4]*Rv[2]+Lv[5]*Rv[3]-Lv[6]*Rv[7]-Lv[7]*Rv[6];
        g[2] = Lv[0]*Rv[2]+Lv[1]*Rv[4]+Lv[2]*Rv[0]-Lv[3]*Rv[6]-Lv[4]*Rv[1]+Lv[5]*Rv[7]+Lv[6]*Rv[3]+Lv[7]*Rv[5];
        g[3] = Lv[0]*Rv[3]+Lv[1]*Rv[5]+Lv[2]*Rv[6]+Lv[3]*Rv[0]-Lv[4]*Rv[7]-Lv[5]*Rv[1]-Lv[6]*Rv[2]-Lv[7]*Rv[4];
        g[4] = Lv[0]*Rv[4]+Lv[1]*Rv[2]-Lv[2]*Rv[1]+Lv[3]*Rv[7]+Lv[4]*Rv[0]-Lv[5]*Rv[6]+Lv[6]*Rv[5]+Lv[7]*Rv[3];
        g[5] = Lv[0]*Rv[5]+Lv[1]*Rv[3]-Lv[2]*Rv[7]-Lv[3]*Rv[1]+Lv[4]*Rv[6]+Lv[5]*Rv[0]-Lv[6]*Rv[4]-Lv[7]*Rv[2];
        g[6] = Lv[0]*Rv[6]+Lv[1]*Rv[7]+Lv[2]*Rv[3]-Lv[3]*Rv[2]-Lv[4]*Rv[5]+Lv[5]*Rv[4]+Lv[6]*Rv[0]+Lv[7]*Rv[1];
        g[7] = Lv[0]*Rv[7]+Lv[1]*Rv[6]-Lv[2]*Rv[5]+Lv[3]*Rv[4]+Lv[4]*Rv[3]-Lv[5]*Rv[2]+Lv[6]*Rv[1]+Lv[7]*Rv[0];
        char* dst = gp_out + (size_t)b_g * 16384 + (size_t)chrow * 2;
#pragma unroll
        for (int i = 0; i < 8; ++i) *(f16*)(dst + (size_t)i * 1024) = (f16)g[i];
    }
}

// ---------------------------------------------------------------------------
// k2: out = gp @ W_out^T + bias, MVLayerNorm, scale.
// Block 16 b x 512 ch, 1024 thr / 16 waves, wave = 16b x 32ch, acc[8][2].
// A (gp) staged via global_load_lds (waves 0-7, 3 bufs); B direct->reg.
// Issue order: B first, then stage. Waits: wv<8 {4,3,0}, wv>=8 {2,2,0}.
// ---------------------------------------------------------------------------
__global__ __launch_bounds__(1024, 4) void k2(
    const char* gp_in, const f16* __restrict__ wo,
    const float* __restrict__ bo_p, const float* __restrict__ an_p,
    float* outp)
{
    __shared__ __align__(16) f16 AsF[3 * 4096];    // [buf][blade8][bat16][k32] 24KB
    __shared__ float red[16][16];

    const int b0 = blockIdx.x * 16;
    const int tid = threadIdx.x, lane = tid & 63, wv = tid >> 6;   // wv 0..15
    const int r_lo = lane & 15, s_hi = lane >> 4;

    // A staging (tid<512, 1 call = 8KB tile)
    const int abl = tid >> 6, arw = (tid >> 2) & 15, agp = (tid & 3) ^ SWZ(arw);
    const char* aS = gp_in + (size_t)(b0 + arw) * 16384 + (size_t)(abl & 7) * 1024 + agp * 16;
    f16* aD = AsF + wv * 512;    // used by wv<8 only

    // A compute-side LDS offset
    const int aoff = r_lo * 32 + ((s_hi ^ SWZ(r_lo)) << 3);   // + blade*512 + buf*4096

    // B direct pointers (per-wave-exclusive W_out rows)
    const int nl0 = wv * 32 + r_lo, nl1 = nl0 + 16;
    const f16* bQ0 = wo + (size_t)nl0 * 512 + s_hi * 8;
    const f16* bQ1 = wo + (size_t)nl1 * 512 + s_hi * 8;

    f32x4 acc[8][2];
    const f32x4 zero = {0.f, 0.f, 0.f, 0.f};
#pragma unroll
    for (int i = 0; i < 8; ++i) { acc[i][0] = zero; acc[i][1] = zero; }

    auto stageA = [&](int kt, int buf) {
        if (tid < 512) GL2LDS(aS + (size_t)kt * 64, aD + buf * 4096);
    };

    f16x8 bregs[2][2];
    // prologue, FIFO = steady pattern: B first, then stages
    bregs[0][0] = *(const f16x8*)bQ0;
    bregs[0][1] = *(const f16x8*)bQ1;
    stageA(0, 0);
    stageA(1, 1);

#pragma unroll
    for (int kt = 0; kt < 16; ++kt) {
        if (kt < 15) {
            bregs[(kt + 1) & 1][0] = *(const f16x8*)(bQ0 + (kt + 1) * 32);
            bregs[(kt + 1) & 1][1] = *(const f16x8*)(bQ1 + (kt + 1) * 32);
        }
        if (kt + 2 < 16) stageA(kt + 2, (kt + 2) % 3);
        if (kt <= 13)      { if (wv < 8) { WAITV(4); } else { WAITV(2); } }
        else if (kt == 14) { if (wv < 8) { WAITV(3); } else { WAITV(2); } }
        else               { WAITV(0); }
        BAR();
        const f16* Ab = AsF + (kt % 3) * 4096;
        const f16x8 b0f = bregs[kt & 1][0];
        const f16x8 b1f = bregs[kt & 1][1];
        {   // blades 0-3
            f16x8 a0 = *(const f16x8*)(Ab + 0 * 512 + aoff);
            f16x8 a1 = *(const f16x8*)(Ab + 1 * 512 + aoff);
            f16x8 a2 = *(const f16x8*)(Ab + 2 * 512 + aoff);
            f16x8 a3 = *(const f16x8*)(Ab + 3 * 512 + aoff);
            PRIO(1);
            acc[0][0] = MFMA_F16(a0, b0f, acc[0][0]); acc[0][1] = MFMA_F16(a0, b1f, acc[0][1]);
            acc[1][0] = MFMA_F16(a1, b0f, acc[1][0]); acc[1][1] = MFMA_F16(a1, b1f, acc[1][1]);
            acc[2][0] = MFMA_F16(a2, b0f, acc[2][0]); acc[2][1] = MFMA_F16(a2, b1f, acc[2][1]);
            acc[3][0] = MFMA_F16(a3, b0f, acc[3][0]); acc[3][1] = MFMA_F16(a3, b1f, acc[3][1]);
            PRIO(0);
        }
        {   // blades 4-7
            f16x8 a4 = *(const f16x8*)(Ab + 4 * 512 + aoff);
            f16x8 a5 = *(const f16x8*)(Ab + 5 * 512 + aoff);
            f16x8 a6 = *(const f16x8*)(Ab + 6 * 512 + aoff);
            f16x8 a7 = *(const f16x8*)(Ab + 7 * 512 + aoff);
            PRIO(1);
            acc[4][0] = MFMA_F16(a4, b0f, acc[4][0]); acc[4][1] = MFMA_F16(a4, b1f, acc[4][1]);
            acc[5][0] = MFMA_F16(a5, b0f, acc[5][0]); acc[5][1] = MFMA_F16(a5, b1f, acc[5][1]);
            acc[6][0] = MFMA_F16(a6, b0f, acc[6][0]); acc[6][1] = MFMA_F16(a6, b1f, acc[6][1]);
            acc[7][0] = MFMA_F16(a7, b0f, acc[7][0]); acc[7][1] = MFMA_F16(a7, b1f, acc[7][1]);
            PRIO(0);
        }
        BAR();
    }

    const float bo0 = bo_p[nl0], bo1 = bo_p[nl1];
    const float an0 = an_p[nl0], an1 = an_p[nl1];

    float partial[4];
#pragma unroll
    for (int rr = 0; rr < 4; ++rr) {
        float o = acc[0][0][rr] + bo0;
        float ss = o * o;
#pragma unroll
        for (int i = 1; i < 8; ++i) ss += acc[i][0][rr] * acc[i][0][rr];
        float s = sqrtf(ss);
        o = acc[0][1][rr] + bo1;
        ss = o * o;
#pragma unroll
        for (int i = 1; i < 8; ++i) ss += acc[i][1][rr] * acc[i][1][rr];
        partial[rr] = s + sqrtf(ss);
    }
#pragma unroll
    for (int off = 1; off < 16; off <<= 1)
#pragma unroll
        for (int rr = 0; rr < 4; ++rr) partial[rr] += __shfl_xor(partial[rr], off);
    if (r_lo == 0)
#pragma unroll
        for (int rr = 0; rr < 4; ++rr) red[s_hi * 4 + rr][wv] = partial[rr];
    __syncthreads();   // full fence: all gp reads done before fp32 stores

#pragma unroll
    for (int rr = 0; rr < 4; ++rr) {
        float tot = 0.f;
#pragma unroll
        for (int w = 0; w < 16; ++w) tot += red[s_hi * 4 + rr][w];
        const float inv = 1.0f / (tot * (1.0f / 512.0f) + 1e-6f);
        const float sc0 = an0 * inv, sc1 = an1 * inv;
        const int b_g = b0 + s_hi * 4 + rr;
        float* dst = outp + (size_t)b_g * 4096;
        f32x4 v;
        v[0] = (acc[0][0][rr] + bo0) * sc0;
        v[1] = acc[1][0][rr] * sc0; v[2] = acc[2][0][rr] * sc0; v[3] = acc[3][0][rr] * sc0;
        *(f32x4*)(dst + (size_t)nl0 * 8) = v;
        v[0] = acc[4][0][rr] * sc0; v[1] = acc[5][0][rr] * sc0;
        v[2] = acc[6][0][rr] * sc0; v[3] = acc[7][0][rr] * sc0;
        *(f32x4*)(dst + (size_t)nl0 * 8 + 4) = v;
        v[0] = (acc[0][1][rr] + bo1) * sc1;
        v[1] = acc[1][1][rr] * sc1; v[2] = acc[2][1][rr] * sc1; v[3] = acc[3][1][rr] * sc1;
        *(f32x4*)(dst + (size_t)nl1 * 8) = v;
        v[0] = acc[4][1][rr] * sc1; v[1] = acc[5][1][rr] * sc1;
        v[2] = acc[6][1][rr] * sc1; v[3] = acc[7][1][rr] * sc1;
        *(f32x4*)(dst + (size_t)nl1 * 8 + 4) = v;
    }
}

// ---------------------------------------------------------------------------
extern "C" void kernel_launch(void* const* d_in, const int* in_sizes, int n_in,
                              void* d_out, int out_size, void* d_ws, size_t ws_size,
                              hipStream_t stream) {
    const float* x  = (const float*)d_in[0];
    const float* wl = (const float*)d_in[1];
    const float* bl = (const float*)d_in[2];
    const float* wr = (const float*)d_in[3];
    const float* br = (const float*)d_in[4];
    const float* wo = (const float*)d_in[5];
    const float* bo = (const float*)d_in[6];
    const float* an = (const float*)d_in[7];
    f16* wf = (f16*)d_ws;
    f16* xt = wf + (1 << 20);   // byte offset 2MB; ws >= 130MB (confirmed R3)

    hipLaunchKernelGGL(k0, dim3(9216), dim3(256), 0, stream, x, wl, wr, wo, wf, xt);
    hipLaunchKernelGGL(k1, dim3(2048), dim3(1024), 0, stream, xt, wf, bl, br, (char*)d_out);
    hipLaunchKernelGGL(k2, dim3(1024), dim3(1024), 0, stream,
                       (const char*)d_out, wf + 524288, bo, an, (float*)d_out);
}